// Round 10
// baseline (1153.494 us; speedup 1.0000x reference)
//
#include <hip/hip_runtime.h>
#include <stdint.h>

#define EN 64
#define BN 32
#define PN 197
#define DIN 768
#define HH 512
#define RHO_ 4.0f

typedef __attribute__((ext_vector_type(8))) short bf16x8;
typedef __attribute__((ext_vector_type(4))) float f32x4;

__device__ __forceinline__ ushort f2bf(float f){
  unsigned u = __float_as_uint(f);
  u += 0x7FFFu + ((u >> 16) & 1u);
  return (ushort)(u >> 16);
}
__device__ __forceinline__ float bf2f(ushort h){ return __uint_as_float(((unsigned)h) << 16); }

// ---------------- prep: bf16 casts + scaled bias ----------------
__global__ __launch_bounds__(256) void prep_kernel(
    const float* __restrict__ etok, const float* __restrict__ mtok,
    const float* __restrict__ ecls, const float* __restrict__ bq,
    ushort* __restrict__ a_ent, ushort* __restrict__ a_men, ushort* __restrict__ a_cls,
    float* __restrict__ bq_s)
{
  int g = blockIdx.x*256 + threadIdx.x;
  int st = gridDim.x*256;
  const float s = 0.04419417382415922f; // 1/sqrt(512)
  for (int i=g; i<(EN*PN*DIN)/4; i+=st){
    float4 v = ((const float4*)etok)[i];
    ushort4 o; o.x=f2bf(v.x); o.y=f2bf(v.y); o.z=f2bf(v.z); o.w=f2bf(v.w);
    ((ushort4*)a_ent)[i] = o;
  }
  for (int i=g; i<(BN*PN*DIN)/4; i+=st){
    float4 v = ((const float4*)mtok)[i];
    ushort4 o; o.x=f2bf(v.x); o.y=f2bf(v.y); o.z=f2bf(v.z); o.w=f2bf(v.w);
    ((ushort4*)a_men)[i] = o;
  }
  for (int i=g; i<(EN*DIN)/4; i+=st){
    float4 v = ((const float4*)ecls)[i];
    ushort4 o; o.x=f2bf(v.x); o.y=f2bf(v.y); o.z=f2bf(v.z); o.w=f2bf(v.w);
    ((ushort4*)a_cls)[i] = o;
  }
  for (int i=g; i<HH; i+=st) bq_s[i] = bq[i]*s;
}

// ---------------- weight transpose via LDS tiles ----------------
__global__ __launch_bounds__(256) void w_transpose(
    const float* __restrict__ Wq, const float* __restrict__ Wk,
    const float* __restrict__ Wv, const float* __restrict__ Wc,
    ushort* __restrict__ Wt)
{
  __shared__ float tl[64][65];
  int mat = blockIdx.z;
  const float* src = (mat==0)?Wq:(mat==1)?Wk:(mat==2)?Wv:Wc;
  float sc = (mat==0)? 0.04419417382415922f : 1.0f;
  int k0 = blockIdx.x*64;
  int n0 = blockIdx.y*64;
  int tid = threadIdx.x;
  int c = tid & 63, r0 = tid >> 6;
  #pragma unroll
  for (int i=0;i<16;++i){
    int r = r0 + i*4;
    tl[r][c] = src[(size_t)(k0+r)*HH + n0+c];
  }
  __syncthreads();
  ushort* dst = Wt + (size_t)mat*HH*DIN;
  #pragma unroll
  for (int i=0;i<16;++i){
    int r = r0 + i*4;
    dst[(size_t)(n0+r)*DIN + k0+c] = f2bf(tl[c][r]*sc);
  }
}

// ---------------- projection GEMMs: C = A @ Wt^T + bias ----------------
__global__ __launch_bounds__(256) void gemm_proj(
    const ushort* __restrict__ a_ent, const ushort* __restrict__ a_men, const ushort* __restrict__ a_cls,
    const ushort* __restrict__ Wt,
    const float* __restrict__ bq_s, const float* __restrict__ bk,
    const float* __restrict__ bv, const float* __restrict__ bc,
    ushort* __restrict__ qo, ushort* __restrict__ ko, ushort* __restrict__ vo,
    float* __restrict__ co)
{
  int x = blockIdx.x;
  int op, mt;
  if (x < 99)        { op = 0; mt = x; }
  else if (x < 149)  { op = 1; mt = x - 99; }
  else if (x < 199)  { op = 2; mt = x - 149; }
  else               { op = 3; mt = 0; }
  int M = (op==0)? EN*PN : (op==3)? EN : BN*PN;
  int m0 = mt*128;
  const ushort* A  = (op==0)? a_ent : (op==3)? a_cls : a_men;
  const ushort* Bw = Wt + (size_t)op*HH*DIN;
  const float* bias = (op==0)? bq_s : (op==1)? bk : (op==2)? bv : bc;
  int n0 = blockIdx.y*128;
  int Mm1 = M-1;

  __shared__ ushort As[128*40];
  __shared__ ushort Bs[128*40];
  int tid = threadIdx.x;
  int lane = tid & 63, wid = tid >> 6;
  int l15 = lane & 15, lg = lane >> 4;
  int wm = wid >> 1, wn = wid & 1;

  f32x4 acc[16];
  #pragma unroll
  for (int i=0;i<16;++i){ f32x4 z = {0.f,0.f,0.f,0.f}; acc[i] = z; }

  bf16x8 sA[2], sB[2];
  #pragma unroll
  for (int i=0;i<2;++i){
    int u = tid + i*256; int row = u>>2; int ko8 = (u&3)*8;
    int rA = m0+row; rA = rA>Mm1 ? Mm1 : rA;
    sA[i] = *(const bf16x8*)(A  + (size_t)rA*DIN + ko8);
    sB[i] = *(const bf16x8*)(Bw + (size_t)(n0+row)*DIN + ko8);
  }
  for (int kt=0; kt<DIN/32; ++kt){
    #pragma unroll
    for (int i=0;i<2;++i){
      int u = tid + i*256; int row = u>>2; int ko8 = (u&3)*8;
      *(bf16x8*)(&As[row*40 + ko8]) = sA[i];
      *(bf16x8*)(&Bs[row*40 + ko8]) = sB[i];
    }
    __syncthreads();
    if (kt < DIN/32 - 1){
      int k0 = (kt+1)*32;
      #pragma unroll
      for (int i=0;i<2;++i){
        int u = tid + i*256; int row = u>>2; int ko8 = (u&3)*8;
        int rA = m0+row; rA = rA>Mm1 ? Mm1 : rA;
        sA[i] = *(const bf16x8*)(A  + (size_t)rA*DIN + k0 + ko8);
        sB[i] = *(const bf16x8*)(Bw + (size_t)(n0+row)*DIN + k0 + ko8);
      }
    }
    bf16x8 af[4], bfg[4];
    #pragma unroll
    for (int t=0;t<4;++t){
      af[t]  = *(const bf16x8*)(&As[(wm*64 + t*16 + l15)*40 + lg*8]);
      bfg[t] = *(const bf16x8*)(&Bs[(wn*64 + t*16 + l15)*40 + lg*8]);
    }
    #pragma unroll
    for (int am=0; am<4; ++am)
      #pragma unroll
      for (int bn=0; bn<4; ++bn)
        acc[am*4+bn] = __builtin_amdgcn_mfma_f32_16x16x32_bf16(af[am], bfg[bn], acc[am*4+bn], 0, 0, 0);
    __syncthreads();
  }

  #pragma unroll
  for (int bn=0; bn<4; ++bn){
    int col = n0 + wn*64 + bn*16 + l15;
    float bval = bias[col];
    #pragma unroll
    for (int am=0; am<4; ++am){
      #pragma unroll
      for (int r=0;r<4;++r){
        int row = m0 + wm*64 + am*16 + lg*4 + r;
        if (row < M){
          float v = acc[am*4+bn][r] + bval;
          if (op==3)      co[(size_t)row*HH + col] = v;
          else if (op==0) qo[(size_t)row*HH + col] = f2bf(v);
          else if (op==1) ko[(size_t)row*HH + col] = f2bf(v);
          else            vo[(size_t)row*HH + col] = f2bf(v);
        }
      }
    }
  }
}

// ---------------- fused attention: BARRIER-FREE QK^T, k read from L1/L2 ----------------
// block=(b,e-pair), 512 thr, 8 waves. Wave owns slot=rnd*8+wid (16 q-rows), 2 rounds.
// k B-fragments loaded per k-slice straight from global (k is 202KB, L1/L2-hot,
// shared by 8 waves + 32 same-b blocks). No __syncthreads in the compute loop —
// waves slip freely; only load[0]-per-slice latency is exposed (counted vmcnt).
__global__ __launch_bounds__(512) void attn_kernel(
    const ushort* __restrict__ qw, const ushort* __restrict__ kw, const ushort* __restrict__ vw,
    const float* __restrict__ cls_fc, const float* __restrict__ maskp,
    const float* __restrict__ mcls, const float* __restrict__ ecls,
    const float* __restrict__ lng, const float* __restrict__ lnb,
    float* __restrict__ outp)
{
  int bid = blockIdx.x;
  int b = bid >> 5;
  int e0 = (bid & 31) * 2;

  __shared__ float w_lds[2][208];
  __shared__ float red[32];

  int tid = threadIdx.x;
  int lane = tid & 63, wid = tid >> 6;
  int l15 = lane & 15, lg = (lane >> 4) & 3;

  for (int i=tid; i<416; i+=512) ((float*)w_lds)[i] = 0.f;
  __syncthreads();                       // w_lds zeroed before any wave's atomics

  const ushort* kb  = kw + (size_t)b*PN*HH;
  const ushort* qb0 = qw + (size_t)e0*PN*HH;
  const ushort* qb1 = qw + (size_t)(e0+1)*PN*HH;

  // per-lane element offsets for the 13 B-fragments (col = ct*16+l15, k-group lg)
  int voff[13];
  #pragma unroll
  for (int ct=0; ct<13; ++ct) voff[ct] = (ct*16 + l15)*HH + lg*8;   // cols>196 read garbage, masked later

  for (int rnd=0; rnd<2; ++rnd){
    int slot = rnd*8 + wid;
    bool active = slot < 13;
    if (active){
      int arow = slot*16 + l15; arow = arow > 196 ? 196 : arow;
      const ushort* q0 = qb0 + (size_t)arow*HH + lg*8;
      const ushort* q1 = qb1 + (size_t)arow*HH + lg*8;

      f32x4 acc[2][13];
      #pragma unroll
      for (int e2=0;e2<2;++e2)
        #pragma unroll
        for (int i=0;i<13;++i){ f32x4 z={0.f,0.f,0.f,0.f}; acc[e2][i]=z; }

      #pragma unroll
      for (int s=0; s<16; ++s){          // 16 k-slices of 32
        bf16x8 bfr[13];
        #pragma unroll
        for (int ct=0; ct<13; ++ct)
          bfr[ct] = *(const bf16x8*)(kb + voff[ct] + s*32);
        bf16x8 qa = *(const bf16x8*)(q0 + s*32);
        bf16x8 qc = *(const bf16x8*)(q1 + s*32);
        #pragma unroll
        for (int ct=0; ct<13; ++ct){
          acc[0][ct] = __builtin_amdgcn_mfma_f32_16x16x32_bf16(qa, bfr[ct], acc[0][ct], 0,0,0);
          acc[1][ct] = __builtin_amdgcn_mfma_f32_16x16x32_bf16(qc, bfr[ct], acc[1][ct], 0,0,0);
        }
      }

      // softmax + column-sum for this slot
      int rt = slot;
      #pragma unroll
      for (int e2=0; e2<2; ++e2){
        if (l15 >= 5){                   // cols 197..207 invalid (ct=12)
          f32x4 ninf = {-1e30f,-1e30f,-1e30f,-1e30f};
          acc[e2][12] = ninf;
        }
        if (rt==0 && lg==0){             // additive mask on query-row 0
          #pragma unroll
          for (int ct=0; ct<13; ++ct){
            int col = ct*16 + l15;
            if (col < 197) acc[e2][ct][0] += RHO_ * maskp[b*PN + col];
          }
        }
        float mrow[4], inv[4];
        #pragma unroll
        for (int r=0;r<4;++r){
          float m = acc[e2][0][r];
          #pragma unroll
          for (int ct=1; ct<13; ++ct) m = fmaxf(m, acc[e2][ct][r]);
          m = fmaxf(m, __shfl_xor(m,1));
          m = fmaxf(m, __shfl_xor(m,2));
          m = fmaxf(m, __shfl_xor(m,4));
          m = fmaxf(m, __shfl_xor(m,8));
          mrow[r] = m;
        }
        #pragma unroll
        for (int r=0;r<4;++r){
          float sm = 0.f;
          #pragma unroll
          for (int ct=0; ct<13; ++ct){
            float ev = __expf(acc[e2][ct][r] - mrow[r]);
            acc[e2][ct][r] = ev;
            sm += ev;
          }
          sm += __shfl_xor(sm,1); sm += __shfl_xor(sm,2);
          sm += __shfl_xor(sm,4); sm += __shfl_xor(sm,8);
          int prow = rt*16 + lg*4 + r;
          inv[r] = (prow < PN) ? 1.0f/sm : 0.f;
        }
        #pragma unroll
        for (int ct=0; ct<13; ++ct){
          float cs = acc[e2][ct][0]*inv[0] + acc[e2][ct][1]*inv[1]
                   + acc[e2][ct][2]*inv[2] + acc[e2][ct][3]*inv[3];
          cs += __shfl_xor(cs,16);
          cs += __shfl_xor(cs,32);
          if (lg==0) atomicAdd(&w_lds[e2][ct*16 + l15], cs);
        }
      }
    }
  }
  __syncthreads();                       // all col-sums in w_lds

  // phase 2: ctx[h] = (1/197) * sum_q w[q]*v[b,q,h]; thread owns h = tid
  const ushort* vb = vw + (size_t)b*PN*HH;
  float cA=0.f, cB=0.f;
  #pragma unroll 4
  for (int q=0; q<PN; ++q){
    float vq = bf2f(vb[(size_t)q*HH + tid]);
    cA += w_lds[0][q]*vq;
    cB += w_lds[1][q]*vq;
  }
  const float invP = 1.0f/197.0f;
  cA*=invP; cB*=invP;

  float sx = cA, sxx = cA*cA, sy = cB, syy = cB*cB;
  #pragma unroll
  for (int off=32; off; off>>=1){
    sx += __shfl_down(sx, off); sxx += __shfl_down(sxx, off);
    sy += __shfl_down(sy, off); syy += __shfl_down(syy, off);
  }
  if (lane==0){ red[wid*4+0]=sx; red[wid*4+1]=sxx; red[wid*4+2]=sy; red[wid*4+3]=syy; }
  __syncthreads();
  float s1A=0.f, s2A=0.f, s1B=0.f, s2B=0.f;
  #pragma unroll
  for (int w=0; w<8; ++w){
    s1A += red[w*4+0]; s2A += red[w*4+1];
    s1B += red[w*4+2]; s2B += red[w*4+3];
  }
  float muA = s1A*(1.f/512.f), muB = s1B*(1.f/512.f);
  float varA = s2A*(1.f/512.f) - muA*muA;
  float varB = s2B*(1.f/512.f) - muB*muB;
  float rsA = rsqrtf(varA + 1e-5f), rsB = rsqrtf(varB + 1e-5f);

  int h = tid;
  float g0=lng[h], bb0=lnb[h];
  float dA = ((cA-muA)*rsA*g0 + bb0) * cls_fc[(size_t)e0*HH + h];
  float dB = ((cB-muB)*rsB*g0 + bb0) * cls_fc[(size_t)(e0+1)*HH + h];

  // g2g: 768 dims over 512 threads (tid; tid+512 for tid<256)
  dA += mcls[b*DIN + tid]*ecls[(size_t)e0*DIN + tid];
  dB += mcls[b*DIN + tid]*ecls[(size_t)(e0+1)*DIN + tid];
  if (tid < 256){
    int j = tid + 512;
    dA += mcls[b*DIN + j]*ecls[(size_t)e0*DIN + j];
    dB += mcls[b*DIN + j]*ecls[(size_t)(e0+1)*DIN + j];
  }

  __syncthreads();
  #pragma unroll
  for (int off=32; off; off>>=1){ dA += __shfl_down(dA, off); dB += __shfl_down(dB, off); }
  if (lane==0){ red[wid*2+0]=dA; red[wid*2+1]=dB; }
  __syncthreads();
  if (tid==0){
    float oA=0.f, oB=0.f;
    #pragma unroll
    for (int w=0; w<8; ++w){ oA += red[w*2+0]; oB += red[w*2+1]; }
    outp[b*EN + e0]   = 0.5f*oA;
    outp[b*EN + e0+1] = 0.5f*oB;
  }
}

extern "C" void kernel_launch(void* const* d_in, const int* in_sizes, int n_in,
                              void* d_out, int out_size, void* d_ws, size_t ws_size,
                              hipStream_t stream)
{
  (void)in_sizes; (void)n_in; (void)out_size; (void)ws_size;
  const float* ecls = (const float*)d_in[0];
  const float* etok = (const float*)d_in[1];
  const float* mcls = (const float*)d_in[2];
  const float* mtok = (const float*)d_in[3];
  const float* maskp= (const float*)d_in[4];
  const float* Wq   = (const float*)d_in[5];
  const float* bq   = (const float*)d_in[6];
  const float* Wk   = (const float*)d_in[7];
  const float* bk   = (const float*)d_in[8];
  const float* Wv   = (const float*)d_in[9];
  const float* bv   = (const float*)d_in[10];
  const float* Wc   = (const float*)d_in[11];
  const float* bc   = (const float*)d_in[12];
  const float* lng  = (const float*)d_in[13];
  const float* lnb  = (const float*)d_in[14];

  char* ws = (char*)d_ws;
  size_t off = 0;
  auto take = [&](size_t bytes){ char* p = ws + off; off += (bytes + 255) & ~(size_t)255; return p; };
  ushort* a_ent = (ushort*)take((size_t)EN*PN*DIN*2);
  ushort* a_men = (ushort*)take((size_t)BN*PN*DIN*2);
  ushort* a_cls = (ushort*)take((size_t)EN*DIN*2);
  ushort* Wt    = (ushort*)take((size_t)4*HH*DIN*2);
  float*  bq_s  = (float*)take((size_t)HH*4);
  ushort* qo    = (ushort*)take((size_t)EN*PN*HH*2);
  ushort* ko    = (ushort*)take((size_t)BN*PN*HH*2);
  ushort* vo    = (ushort*)take((size_t)BN*PN*HH*2);
  float*  co    = (float*)take((size_t)EN*HH*4);

  prep_kernel<<<1024, 256, 0, stream>>>(etok, mtok, ecls, bq, a_ent, a_men, a_cls, bq_s);
  w_transpose<<<dim3(12,8,4), 256, 0, stream>>>(Wq, Wk, Wv, Wc, Wt);
  gemm_proj<<<dim3(200,4,1), 256, 0, stream>>>(a_ent, a_men, a_cls, Wt,
                                               bq_s, bk, bv, bc, qo, ko, vo, co);
  attn_kernel<<<1024, 512, 0, stream>>>(qo, ko, vo, co, maskp, mcls, ecls,
                                        lng, lnb, (float*)d_out);
}